// Round 17
// baseline (67.109 us; speedup 1.0000x reference)
//
#include <hip/hip_runtime.h>

#define B_ 4
#define N_ 512
#define D_ 768
#define A_ 128

typedef short bf16x8 __attribute__((ext_vector_type(8)));
typedef ushort u16x8 __attribute__((ext_vector_type(8)));
typedef ushort u16x4 __attribute__((ext_vector_type(4)));
typedef float f32x4 __attribute__((ext_vector_type(4)));

__device__ __forceinline__ ushort f2h(float x) {  // f32 -> bf16 bits, RNE
  uint u = __builtin_bit_cast(uint, x);
  return (ushort)((u + 0x7fffu + ((u >> 16) & 1u)) >> 16);
}
__device__ __forceinline__ float h2f(ushort h) {
  uint u = ((uint)h) << 16;
  return __builtin_bit_cast(float, u);
}
__device__ __forceinline__ bf16x8 ld8(const ushort* p) {
  return *(const bf16x8*)p;
}
#define MFMA(a, b, c) __builtin_amdgcn_mfma_f32_16x16x32_bf16(a, b, c, 0, 0, 0)

// ---------------------------------------------------------------------------
// k0: fused prep (+ uvec = -2*v write). Unchanged from R16.
// ---------------------------------------------------------------------------
__global__ __launch_bounds__(256) void k0_prep(
    const float* __restrict__ M, const float* __restrict__ W1,
    const float* __restrict__ W2, const float* __restrict__ vw,
    ushort* __restrict__ Mr_h, ushort* __restrict__ Mr_l,
    ushort* __restrict__ Mt_h, ushort* __restrict__ Mt_l,
    ushort* __restrict__ Wt_h, ushort* __restrict__ Wt_l,
    float* __restrict__ uvec) {
  __shared__ ushort lds_h[64][40];
  __shared__ ushort lds_l[64][40];
  const int t = threadIdx.x;
  const int bid = blockIdx.x;
  if (bid < 768) {  // ---- M part ----
    const int dq = bid % 12;
    const int rest = bid / 12;
    const int d0 = dq * 64;
    const int n0 = (rest & 15) * 32;
    const int b = rest >> 4;
    const int n = t >> 3;          // 0..31
    const int dg = (t & 7) * 8;    // 0..56
    const size_t roff = ((size_t)(b * N_ + n0 + n)) * D_ + d0 + dg;
    const float4 v0 = *(const float4*)(M + roff);
    const float4 v1 = *(const float4*)(M + roff + 4);
    const float x[8] = {v0.x, v0.y, v0.z, v0.w, v1.x, v1.y, v1.z, v1.w};
    u16x8 vh, vl;
#pragma unroll
    for (int e = 0; e < 8; ++e) {
      ushort h = f2h(x[e]);
      ushort l = f2h(x[e] - h2f(h));
      vh[e] = h;
      vl[e] = l;
      lds_h[dg + e][n] = h;
      lds_l[dg + e][n] = l;
    }
    *(u16x8*)(Mr_h + roff) = vh;
    *(u16x8*)(Mr_l + roff) = vl;
    __syncthreads();
    const int dd = t >> 2;          // 0..63
    const int ng = (t & 3) * 8;     // 0..24
    const size_t toff = ((size_t)b * D_ + d0 + dd) * N_ + n0 + ng;
    *(u16x8*)(Mt_h + toff) = *(const u16x8*)(&lds_h[dd][ng]);
    *(u16x8*)(Mt_l + toff) = *(const u16x8*)(&lds_l[dd][ng]);
  } else {  // ---- W part ----
    const int c = t;
    const int k0 = (bid - 768) * 8;
    const float* __restrict__ Wp = (c < A_) ? W1 : W2;
    const int cc = c & (A_ - 1);
    u16x8 vh, vl;
#pragma unroll
    for (int e = 0; e < 8; ++e) {
      float x = Wp[(size_t)(k0 + e) * A_ + cc];
      ushort h = f2h(x);
      vh[e] = h;
      vl[e] = f2h(x - h2f(h));
    }
    *(u16x8*)(Wt_h + (size_t)c * D_ + k0) = vh;
    *(u16x8*)(Wt_l + (size_t)c * D_ + k0) = vl;
    if (bid == 768 && c < A_) uvec[c] = -2.f * vw[c];
  }
}

// ---------------------------------------------------------------------------
// k1 v4: M @ [W1|W2] -> EXPONENTIALS (unchanged from R16; E2 bf16 out).
// ---------------------------------------------------------------------------
__global__ __launch_bounds__(256) void k1_mfma(
    const ushort* __restrict__ Mr_h, const ushort* __restrict__ Mr_l,
    const ushort* __restrict__ Wt_h, const ushort* __restrict__ Wt_l,
    const float* __restrict__ b1, const float* __restrict__ b2,
    float* __restrict__ w1e, ushort* __restrict__ w2e) {
  __shared__ float l_red[4][32][33];  // 16.9 KB
  const int t = threadIdx.x;
  const int l = t & 63;
  const int w = t >> 6;
  const int r = l & 15, g = l >> 4;
  const int row0 = blockIdx.x * 32;
  const int cb = blockIdx.y * 32;
  const int kbase = w * 192;  // wave-private K-range (6 K-steps of 32)
  const size_t oA = (size_t)(row0 + r) * D_ + kbase + g * 8;
  const size_t oA2 = oA + (size_t)16 * D_;
  const size_t oB = (size_t)(cb + r) * D_ + kbase + g * 8;
  const size_t oB2 = oB + (size_t)16 * D_;
  f32x4 acc[2][2] = {};
  bf16x8 A[2][4], Bv[2][4];
#define K1LOAD(s, k0)                                                        \
  A[s][0] = ld8(Mr_h + oA + (k0));  A[s][1] = ld8(Mr_h + oA2 + (k0));        \
  A[s][2] = ld8(Mr_l + oA + (k0));  A[s][3] = ld8(Mr_l + oA2 + (k0));        \
  Bv[s][0] = ld8(Wt_h + oB + (k0)); Bv[s][1] = ld8(Wt_h + oB2 + (k0));       \
  Bv[s][2] = ld8(Wt_l + oB + (k0)); Bv[s][3] = ld8(Wt_l + oB2 + (k0));
#define K1MM(s)                                                              \
  acc[0][0] = MFMA(A[s][0], Bv[s][0], acc[0][0]);                            \
  acc[0][0] = MFMA(A[s][0], Bv[s][2], acc[0][0]);                            \
  acc[0][0] = MFMA(A[s][2], Bv[s][0], acc[0][0]);                            \
  acc[0][1] = MFMA(A[s][0], Bv[s][1], acc[0][1]);                            \
  acc[0][1] = MFMA(A[s][0], Bv[s][3], acc[0][1]);                            \
  acc[0][1] = MFMA(A[s][2], Bv[s][1], acc[0][1]);                            \
  acc[1][0] = MFMA(A[s][1], Bv[s][0], acc[1][0]);                            \
  acc[1][0] = MFMA(A[s][1], Bv[s][2], acc[1][0]);                            \
  acc[1][0] = MFMA(A[s][3], Bv[s][0], acc[1][0]);                            \
  acc[1][1] = MFMA(A[s][1], Bv[s][1], acc[1][1]);                            \
  acc[1][1] = MFMA(A[s][1], Bv[s][3], acc[1][1]);                            \
  acc[1][1] = MFMA(A[s][3], Bv[s][1], acc[1][1]);
  K1LOAD(0, 0)
#pragma unroll
  for (int kt = 0; kt < 6; ++kt) {
    if (kt & 1) {
      if (kt < 5) { K1LOAD(0, (kt + 1) * 32) }
      K1MM(1)
    } else {
      if (kt < 5) { K1LOAD(1, (kt + 1) * 32) }
      K1MM(0)
    }
  }
#undef K1LOAD
#undef K1MM
#pragma unroll
  for (int fi = 0; fi < 2; ++fi)
#pragma unroll
    for (int fj = 0; fj < 2; ++fj)
#pragma unroll
      for (int rr = 0; rr < 4; ++rr)
        l_red[w][fi * 16 + g * 4 + rr][fj * 16 + r] = acc[fi][fj][rr];
  __syncthreads();

  const float SC = 2.8853900817779268f;  // 2*log2(e): e^{2x} = 2^{SC*x}
  const int b = row0 >> 9;
  const int n0 = row0 & (N_ - 1);
  if (cb < A_) {  // E1: w1e[row][col] f32, col-fast coalesced
#pragma unroll
    for (int k = 0; k < 4; ++k) {
      const int row = (t >> 5) + k * 8;
      const int col = t & 31;
      float v = l_red[0][row][col] + l_red[1][row][col] +
                l_red[2][row][col] + l_red[3][row][col];
      v = (v + b1[cb + col]) * SC;
      w1e[(size_t)(row0 + row) * A_ + cb + col] = __builtin_amdgcn_exp2f(v);
    }
  } else {  // E2: w2e[(b*128 + a)*512 + n] BF16, row(n)-fast
#pragma unroll
    for (int k = 0; k < 4; ++k) {
      const int row = t & 31;
      const int col = (t >> 5) + k * 8;
      float v = l_red[0][row][col] + l_red[1][row][col] +
                l_red[2][row][col] + l_red[3][row][col];
      v = (v + b2[cb - A_ + col]) * SC;
      w2e[(size_t)(b * A_ + cb - A_ + col) * N_ + n0 + row] =
          f2h(__builtin_amdgcn_exp2f(v));
    }
  }
}

// ---------------------------------------------------------------------------
// k2 v17: MAX OCCUPANCY — wave = (row, j-QUARTER): 8192 waves = 32/CU =
// 8/SIMD (was 16/CU; TLP is the only lever that has moved this kernel).
// Block = 512 thr = 2 rows x 4 quarters; grid 1024 (4 blocks/CU);
// LDS [2][16][512] bf16 = 32 KB. Lane owns 2 j: ds_read_b32 (2 bf16,
// 2-way bank = free), unpack = 1 shl + 1 and. launch_bounds(512,8) caps
// VGPR 64 (live ~40). Cross-quarter softmax via tiny LDS (4-way merge).
// ---------------------------------------------------------------------------
__global__ __launch_bounds__(512, 8) void k2_scores(
    const float* __restrict__ w1e, const ushort* __restrict__ w2e,
    const float* __restrict__ uvec, const int* __restrict__ mask,
    const float* __restrict__ vw, ushort* __restrict__ ah,
    ushort* __restrict__ al) {
  __shared__ ushort l_w2[2][16][N_];  // 32 KB: [buf][a_local][j] bf16
  __shared__ float l_red[2][4];
  __shared__ float l_sum[2][4];
  const int t = threadIdx.x;
  const int lane = t & 63;
  const int w = t >> 6;   // 0..7
  const int r = w >> 2;   // row in block 0..1
  const int q = w & 3;    // j-quarter
  const int i0 = blockIdx.x * 2;
  const int b = i0 >> 9;
  const int i = i0 + r;
  const int iu = __builtin_amdgcn_readfirstlane(i);
  const float* __restrict__ w1row = w1e + (size_t)iu * A_;  // scalar loads

  float vs = vw[lane] + vw[64 + lane];  // Vsum via butterfly
#pragma unroll
  for (int off = 32; off; off >>= 1) vs += __shfl_xor(vs, off);

  const ushort* __restrict__ w2src = w2e + (size_t)b * A_ * N_;
  u16x8 st[2];  // staging: chunk = 16 a x 512 j bf16 = 1024 x 16B / 512 thr

#define STAGE_LOAD(cc)                                                      \
  {                                                                         \
    const ushort* __restrict__ src = w2src + (size_t)(cc) * 16 * N_;        \
    _Pragma("unroll") for (int k = 0; k < 2; ++k) {                         \
      const int f = t + k * 512;                                            \
      st[k] = *(const u16x8*)(src + (size_t)(f >> 6) * N_ + (f & 63) * 8);  \
    }                                                                       \
  }
#define STAGE_WRITE(bf)                                                     \
  {                                                                         \
    _Pragma("unroll") for (int k = 0; k < 2; ++k) {                         \
      const int f = t + k * 512;                                            \
      *(u16x8*)(&l_w2[bf][f >> 6][(f & 63) * 8]) = st[k];                   \
    }                                                                       \
  }

  STAGE_LOAD(0)
  STAGE_WRITE(0)
  __syncthreads();

  const int jq = q * 128 + lane * 2;  // this lane's 2 j columns
  float sx = 0.f, sy = 0.f;
#pragma unroll 1
  for (int cc = 0; cc < 8; ++cc) {
    if (cc + 1 < 8) STAGE_LOAD(cc + 1)  // issue early (T14)
    const ushort(*wb)[N_] = l_w2[cc & 1];
#pragma unroll 1
    for (int aa = 0; aa < 4; ++aa) {
      const float4 wa = *(const float4*)(w1row + cc * 16 + aa * 4);  // s_load
      const float4 uu = *(const float4*)(uvec + cc * 16 + aa * 4);   // s_load
      const float wa_[4] = {wa.x, wa.y, wa.z, wa.w};
      const float uu_[4] = {uu.x, uu.y, uu.z, uu.w};
#pragma unroll
      for (int e = 0; e < 4; ++e) {
        const float wx = wa_[e];
        const float ux = uu_[e];
        const uint xr = *(const uint*)(&wb[aa * 4 + e][jq]);  // b32: 2 bf16
        const float x0 = __builtin_bit_cast(float, xr << 16);
        const float x1 = __builtin_bit_cast(float, xr & 0xffff0000u);
        sx = fmaf(ux, __builtin_amdgcn_rcpf(fmaf(wx, x0, 1.f)), sx);
        sy = fmaf(ux, __builtin_amdgcn_rcpf(fmaf(wx, x1, 1.f)), sy);
      }
    }
    if (cc + 1 < 8) { STAGE_WRITE((cc + 1) & 1) }  // write late (T14)
    __syncthreads();
  }
#undef STAGE_LOAD
#undef STAGE_WRITE

  // masks (int2), then scores
  const float NEG = -3.402823466e38f;  // np.finfo(f32).min
  const int2 mk = *(const int2*)(mask + (size_t)i * N_ + jq);
  sx = mk.x ? (vs + sx) : NEG;
  sy = mk.y ? (vs + sy) : NEG;

  // softmax: wave-local max -> cross-quarter merge via LDS
  float rmax = fmaxf(sx, sy);
#pragma unroll
  for (int off = 32; off; off >>= 1) rmax = fmaxf(rmax, __shfl_xor(rmax, off));
  if (lane == 0) l_red[r][q] = rmax;
  __syncthreads();
  rmax = fmaxf(fmaxf(l_red[r][0], l_red[r][1]),
               fmaxf(l_red[r][2], l_red[r][3]));

  const float L2E = 1.4426950408889634f;
  // all-masked row: s-rmax = 0 -> 1 -> uniform 1/512 (ref match);
  // masked in live row: (NEG-rmax)*L2E -> -inf -> exp2 = 0 exactly.
  sx = __builtin_amdgcn_exp2f((sx - rmax) * L2E);
  sy = __builtin_amdgcn_exp2f((sy - rmax) * L2E);
  float psum = sx + sy;
#pragma unroll
  for (int off = 32; off; off >>= 1) psum += __shfl_xor(psum, off);
  if (lane == 0) l_sum[r][q] = psum;
  __syncthreads();
  const float inv = __builtin_amdgcn_rcpf(
      (l_sum[r][0] + l_sum[r][1]) + (l_sum[r][2] + l_sum[r][3]));

  const float p0 = sx * inv;
  const float p1 = sy * inv;
  const ushort h0 = f2h(p0);
  const ushort h1 = f2h(p1);
  const ushort g0 = f2h(p0 - h2f(h0));
  const ushort g1 = f2h(p1 - h2f(h1));
  const size_t base = (size_t)i * N_ + jq;
  *(uint*)(ah + base) = (uint)h0 | ((uint)h1 << 16);
  *(uint*)(al + base) = (uint)g0 | ((uint)g1 << 16);
}

// ---------------------------------------------------------------------------
// k3 v4: out[b] = attn[b] @ M[b] (unchanged from R16).
// ---------------------------------------------------------------------------
__global__ __launch_bounds__(256) void k3_mfma(
    const ushort* __restrict__ ah, const ushort* __restrict__ al,
    const ushort* __restrict__ Mt_h, const ushort* __restrict__ Mt_l,
    float* __restrict__ out) {
  __shared__ float l_red[4][64][33];  // 33.8 KB
  const int t = threadIdx.x;
  const int l = t & 63;
  const int w = t >> 6;
  const int r = l & 15, g = l >> 4;
  const int row0 = blockIdx.x * 64;    // global row b*N+i (64 | 512)
  const int d0 = blockIdx.y * 32;
  const int b = row0 >> 9;
  const int jbase = w * 128;  // wave-private j-range (4 K-steps of 32)
  const ushort* __restrict__ Bh = Mt_h + (size_t)b * D_ * N_;
  const ushort* __restrict__ Bl = Mt_l + (size_t)b * D_ * N_;
  size_t oA[4];
#pragma unroll
  for (int fi = 0; fi < 4; ++fi)
    oA[fi] = (size_t)(row0 + fi * 16 + r) * N_ + jbase + g * 8;
  const size_t oB = (size_t)(d0 + r) * N_ + jbase + g * 8;
  const size_t oB2 = oB + (size_t)16 * N_;
  f32x4 acc[4][2] = {};
  bf16x8 A[2][8], Bv[2][4];
#define K3LOAD(s, j0)                                                        \
  A[s][0] = ld8(ah + oA[0] + (j0)); A[s][1] = ld8(ah + oA[1] + (j0));        \
  A[s][2] = ld8(ah + oA[2] + (j0)); A[s][3] = ld8(ah + oA[3] + (j0));        \
  A[s][4] = ld8(al + oA[0] + (j0)); A[s][5] = ld8(al + oA[1] + (j0));        \
  A[s][6] = ld8(al + oA[2] + (j0)); A[s][7] = ld8(al + oA[3] + (j0));        \
  Bv[s][0] = ld8(Bh + oB + (j0));   Bv[s][1] = ld8(Bh + oB2 + (j0));         \
  Bv[s][2] = ld8(Bl + oB + (j0));   Bv[s][3] = ld8(Bl + oB2 + (j0));
#define K3MM(s)                                                              \
  _Pragma("unroll") for (int fi = 0; fi < 4; ++fi)                           \
  _Pragma("unroll") for (int fd = 0; fd < 2; ++fd) {                         \
    acc[fi][fd] = MFMA(A[s][fi], Bv[s][fd], acc[fi][fd]);                    \
    acc[fi][fd] = MFMA(A[s][fi], Bv[s][fd + 2], acc[fi][fd]);                \
    acc[fi][fd] = MFMA(A[s][fi + 4], Bv[s][fd], acc[fi][fd]);                \
  }
  K3LOAD(0, 0)
#pragma unroll
  for (int kt = 0; kt < 4; ++kt) {
    if (kt & 1) {
      if (kt < 3) { K3LOAD(0, (kt + 1) * 32) }
      K3MM(1)
    } else {
      if (kt < 3) { K3LOAD(1, (kt + 1) * 32) }
      K3MM(0)
    }
  }
#undef K3LOAD
#undef K3MM
#pragma unroll
  for (int fi = 0; fi < 4; ++fi)
#pragma unroll
    for (int fd = 0; fd < 2; ++fd)
#pragma unroll
      for (int rr = 0; rr < 4; ++rr)
        l_red[w][fi * 16 + g * 4 + rr][fd * 16 + r] = acc[fi][fd][rr];
  __syncthreads();
#pragma unroll
  for (int k = 0; k < 8; ++k) {
    const int row = (t >> 5) + k * 8;
    const int col = t & 31;
    const float v = l_red[0][row][col] + l_red[1][row][col] +
                    l_red[2][row][col] + l_red[3][row][col];
    out[(size_t)(row0 + row) * D_ + d0 + col] = v;
  }
}

extern "C" void kernel_launch(void* const* d_in, const int* in_sizes, int n_in,
                              void* d_out, int out_size, void* d_ws,
                              size_t ws_size, hipStream_t stream) {
  const float* M = (const float*)d_in[0];
  const int* mask = (const int*)d_in[1];
  const float* W1 = (const float*)d_in[2];
  const float* b1 = (const float*)d_in[3];
  const float* W2 = (const float*)d_in[4];
  const float* b2 = (const float*)d_in[5];
  const float* vw = (const float*)d_in[6];
  float* out = (float*)d_out;

  // workspace carve-up: ~18.25 MB total
  float* w1e = (float*)d_ws;                      // [2048][128] f32   1 MB
  ushort* w2eb = (ushort*)(w1e + 2048 * A_);      // [4][128][512] bf16 .5 MB
  ushort* ah = w2eb + 4 * A_ * N_;                // [2048][512] bf16  2 MB
  ushort* al = ah + 2048 * N_;                    //                   2 MB
  ushort* Mr_h = al + 2048 * N_;                  // [2048][768] bf16  3 MB
  ushort* Mr_l = Mr_h + 2048 * D_;                //                   3 MB
  ushort* Mt_h = Mr_l + 2048 * D_;                // [4][768][512]     3 MB
  ushort* Mt_l = Mt_h + 2048 * D_;                //                   3 MB
  ushort* Wt_h = Mt_l + 2048 * D_;                // [256][768] bf16   .375
  ushort* Wt_l = Wt_h + 256 * D_;                 //                   .375
  float* uvec = (float*)(Wt_l + 256 * D_);        // [128] f32         512B

  k0_prep<<<864, 256, 0, stream>>>(M, W1, W2, vw, Mr_h, Mr_l, Mt_h, Mt_l,
                                   Wt_h, Wt_l, uvec);
  k1_mfma<<<dim3(2048 / 32, 8), 256, 0, stream>>>(Mr_h, Mr_l, Wt_h, Wt_l,
                                                  b1, b2, w1e, w2eb);
  k2_scores<<<(B_ * N_) / 2, 512, 0, stream>>>(w1e, w2eb, uvec, mask, vw,
                                               ah, al);
  k3_mfma<<<dim3(2048 / 64, D_ / 32), 256, 0, stream>>>(ah, al, Mt_h, Mt_l,
                                                        out);
}